// Round 17
// baseline (322.931 us; speedup 1.0000x reference)
//
#include <hip/hip_runtime.h>
#include <hip/hip_bf16.h>

// ---------------- problem constants ----------------
constexpr int Bg  = 8;       // graphs
constexpr int Nn  = 1024;    // nodes per graph
constexpr int Cc  = 256;     // channels
constexpr int Hh  = 8;       // heads
constexpr int DKh = 32;      // head dim
constexpr int Ee  = 131072;  // edges
constexpr int BNn = Bg * Nn; // 8192 total nodes
#define EPSV 1e-5f

// Fragment formula everywhere (R29-R31 validated; KT = K/32):
//   idx(row,col) = ((row>>4)*KT + (col>>5))*512 + (row&15)*32 + (col&31)

typedef __attribute__((ext_vector_type(8))) short bf16x8;
typedef __attribute__((ext_vector_type(4))) float f32x4;

static __device__ __forceinline__ unsigned short f2b(float v) {
    __hip_bfloat16 h = __float2bfloat16(v);
    return __builtin_bit_cast(unsigned short, h);
}
static __device__ __forceinline__ float b2f(unsigned short u) {
    unsigned int x = ((unsigned int)u) << 16;
    return __builtin_bit_cast(float, x);
}
static __device__ __forceinline__ bf16x8 ldb8(const unsigned short* p) {
    return *(const bf16x8*)p;
}

// ---------------- fused prep: xconv + wconv + hist ----------------
__global__ __launch_bounds__(256) void prep_k(
    const float* __restrict__ x, unsigned short* __restrict__ xf,
    unsigned short* __restrict__ xlo,
    const float* __restrict__ Wr, const float* __restrict__ Wn,
    const float* __restrict__ Wq, const float* __restrict__ Wk,
    const float* __restrict__ Wv, const float* __restrict__ Wo,
    const float* __restrict__ W1, const float* __restrict__ W2,
    unsigned short* __restrict__ WcatT,
    unsigned short* __restrict__ WqT, unsigned short* __restrict__ WkT,
    unsigned short* __restrict__ WvT, unsigned short* __restrict__ WoT,
    unsigned short* __restrict__ W1T, unsigned short* __restrict__ W2T,
    const int* __restrict__ ei, int* __restrict__ deg)
{
    int blk = blockIdx.x;
    if (blk < 2048) {
        int i = (blk * 256 + threadIdx.x) * 4;
        float4 v = *(const float4*)(x + i);
        int r = i >> 8, c = i & 255;
        ushort4 pk;
        pk.x = f2b(v.x); pk.y = f2b(v.y); pk.z = f2b(v.z); pk.w = f2b(v.w);
        *(ushort4*)(xlo + (size_t)r * 256 + c) = pk;       // row-major (gather src)
        *(ushort4*)(xf + ((size_t)(r >> 4) * 16 + (c >> 5)) * 512
                    + (r & 15) * 32 + (c & 31)) = pk;      // fragment (GEMM A)
    } else if (blk < 4608) {
        int idx = (blk - 2048) * 256 + threadIdx.x;
        if (idx < 131072) {                      // WcatT frag [n/16][k/32][16][32], K=512
            int n = idx >> 9, k = idx & 511;
            float v = (k < 256) ? Wr[k * 256 + n] : Wn[(k - 256) * 256 + n];
            WcatT[((size_t)(n >> 4) * 16 + (k >> 5)) * 512 + (n & 15) * 32 + (k & 31)] = f2b(v);
        } else if (idx < 393216) {               // q,k,v,o frag, K=256
            int l = idx - 131072;
            int wsel = l >> 16; l &= 65535;
            int n = l >> 8, kk = l & 255;
            const float* S = wsel == 0 ? Wq : wsel == 1 ? Wk : wsel == 2 ? Wv : Wo;
            unsigned short* D = wsel == 0 ? WqT : wsel == 1 ? WkT : wsel == 2 ? WvT : WoT;
            D[((size_t)(n >> 4) * 8 + (kk >> 5)) * 512 + (n & 15) * 32 + (kk & 31)]
                = f2b(S[kk * 256 + n]);
        } else if (idx < 524288) {               // W1 frag [512 cols], K=256
            int l = idx - 393216;
            int n = l >> 8, kk = l & 255;
            W1T[((size_t)(n >> 4) * 8 + (kk >> 5)) * 512 + (n & 15) * 32 + (kk & 31)]
                = f2b(W1[kk * 512 + n]);
        } else {                                 // W2 frag [256 cols], K=512
            int l = idx - 524288;
            int n = l >> 9, kk = l & 511;
            W2T[((size_t)(n >> 4) * 16 + (kk >> 5)) * 512 + (n & 15) * 32 + (kk & 31)]
                = f2b(W2[kk * 256 + n]);
        }
    } else {
        int e = (blk - 4608) * 256 + threadIdx.x;
        atomicAdd(&deg[ei[Ee + e]], 1);
    }
}

// ---------------- CSR scan (coalesced, interleaved buckets) ----------------
__global__ __launch_bounds__(256) void scan_k(
    const int* __restrict__ deg, int* __restrict__ rowst, int* __restrict__ cursor)
{
    __shared__ int partial[256];
    int t = threadIdx.x;
    int local[32];
    int s = 0;
    #pragma unroll
    for (int i = 0; i < 32; ++i) { local[i] = deg[i * 256 + t]; s += local[i]; }
    partial[t] = s;
    __syncthreads();
    for (int off = 1; off < 256; off <<= 1) {
        int v = (t >= off) ? partial[t - off] : 0;
        __syncthreads();
        partial[t] += v;
        __syncthreads();
    }
    int base = partial[t] - s;
    #pragma unroll
    for (int i = 0; i < 32; ++i) {
        int n = i * 256 + t;
        rowst[n] = base;
        cursor[n] = base;
        base += local[i];
    }
}

__global__ __launch_bounds__(256) void place_k(
    const int* __restrict__ ei, int* __restrict__ cursor, int* __restrict__ eidx)
{
    int e = blockIdx.x * 256 + threadIdx.x;
    int s = ei[e], d = ei[Ee + e];
    int pos = atomicAdd(&cursor[d], 1);
    eidx[pos] = s;
}

// ---------------- merged gather (blocks 0..2047) + QKV GEMM (2048..5119) ----------------
__global__ __launch_bounds__(256, 4) void gather_qkv_k(
    const unsigned short* __restrict__ xlo, const int* __restrict__ rowst,
    const int* __restrict__ deg, const int* __restrict__ eidx,
    unsigned short* __restrict__ xf,
    const unsigned short* __restrict__ WT,
    const float* __restrict__ bq, const float* __restrict__ bk,
    const float* __restrict__ bv,
    unsigned short* __restrict__ qb, unsigned short* __restrict__ kb,
    unsigned short* __restrict__ vTb, float qscale)
{
    __shared__ unsigned short vtile[64][40];
    int blk = blockIdx.x;

    if (blk < 2048) {
        // gather: 4 nodes per block, one 64-lane wave each (bf16 row-major src)
        int n = blk * 4 + (threadIdx.x >> 6);
        int c4 = (threadIdx.x & 63) * 4;
        int b0 = rowst[n], d = deg[n];
        float4 acc = {0.f, 0.f, 0.f, 0.f};
        int i = 0;
        for (; i + 4 <= d; i += 4) {
            int s0 = eidx[b0 + i], s1 = eidx[b0 + i + 1];
            int s2 = eidx[b0 + i + 2], s3 = eidx[b0 + i + 3];
            ushort4 a0 = *(const ushort4*)(xlo + (size_t)s0 * 256 + c4);
            ushort4 a1 = *(const ushort4*)(xlo + (size_t)s1 * 256 + c4);
            ushort4 a2 = *(const ushort4*)(xlo + (size_t)s2 * 256 + c4);
            ushort4 a3 = *(const ushort4*)(xlo + (size_t)s3 * 256 + c4);
            acc.x += (b2f(a0.x) + b2f(a1.x)) + (b2f(a2.x) + b2f(a3.x));
            acc.y += (b2f(a0.y) + b2f(a1.y)) + (b2f(a2.y) + b2f(a3.y));
            acc.z += (b2f(a0.z) + b2f(a1.z)) + (b2f(a2.z) + b2f(a3.z));
            acc.w += (b2f(a0.w) + b2f(a1.w)) + (b2f(a2.w) + b2f(a3.w));
        }
        for (; i < d; ++i) {
            int s = eidx[b0 + i];
            ushort4 a = *(const ushort4*)(xlo + (size_t)s * 256 + c4);
            acc.x += b2f(a.x); acc.y += b2f(a.y);
            acc.z += b2f(a.z); acc.w += b2f(a.w);
        }
        ushort4 pk;
        pk.x = f2b(acc.x); pk.y = f2b(acc.y); pk.z = f2b(acc.z); pk.w = f2b(acc.w);
        int cg2 = 256 + c4;                    // agg occupies cols 256..511 of xf
        *(ushort4*)(xf + ((size_t)(n >> 4) * 16 + (cg2 >> 5)) * 512
                    + (n & 15) * 32 + (cg2 & 31)) = pk;
        return;
    }

    // QKV GEMM, N=768 = [q|k|v]; fragment A (xf kts 0..7) + fragment B
    int qblk = blk - 2048;
    const int n0 = (qblk % 12) * 64;
    const int m0 = (qblk / 12) * 32;
    const int t = threadIdx.x;
    const int wave = t >> 6, lane = t & 63;
    const int tl = lane & 15, g = lane >> 4;
    const int wr = wave >> 1, wc = wave & 1;
    const int which = n0 >> 8;               // 0:q 1:k 2:v

    f32x4 acc[2] = {};

    const unsigned short* a0 = xf + (size_t)((m0 >> 4) + wr) * 16 * 512 + tl * 32 + g * 8;
    const unsigned short* b0 = WT + ((size_t)(n0 >> 4) + wc * 2) * 8 * 512 + tl * 32 + g * 8;
    const unsigned short* b1 = b0 + 8 * 512;

    for (int k0 = 0; k0 < 256; k0 += 32) {
        bf16x8 af  = ldb8(a0 + (k0 >> 5) * 512);
        bf16x8 bf0 = ldb8(b0 + (k0 >> 5) * 512), bf1 = ldb8(b1 + (k0 >> 5) * 512);
        acc[0] = __builtin_amdgcn_mfma_f32_16x16x32_bf16(af, bf0, acc[0], 0, 0, 0);
        acc[1] = __builtin_amdgcn_mfma_f32_16x16x32_bf16(af, bf1, acc[1], 0, 0, 0);
    }

    const float* bias = which == 0 ? bq : which == 1 ? bk : bv;
    const float sc = which == 0 ? qscale : 1.f;

    if (which == 0) {
        #pragma unroll
        for (int c16 = 0; c16 < 2; ++c16)
            #pragma unroll
            for (int reg = 0; reg < 4; ++reg) {
                int row = m0 + wr * 16 + g * 4 + reg;
                int col = (n0 & 255) + wc * 32 + c16 * 16 + tl;
                qb[(size_t)row * Cc + col] = f2b((acc[c16][reg] + bias[col]) * sc);
            }
    } else if (which == 1) {
        // K fragment layout: kf[(row>>4)*8 + (col>>5)][row&15][col&31]
        #pragma unroll
        for (int c16 = 0; c16 < 2; ++c16)
            #pragma unroll
            for (int reg = 0; reg < 4; ++reg) {
                int row = m0 + wr * 16 + g * 4 + reg;
                int col = (n0 & 255) + wc * 32 + c16 * 16 + tl;
                kb[((size_t)(row >> 4) * 8 + (col >> 5)) * 512
                   + (row & 15) * 32 + (col & 31)] = f2b(acc[c16][reg] + bias[col]);
            }
    } else {
        #pragma unroll
        for (int c16 = 0; c16 < 2; ++c16)
            #pragma unroll
            for (int reg = 0; reg < 4; ++reg) {
                int colL = wc * 32 + c16 * 16 + tl;
                int rowL = wr * 16 + g * 4 + reg;
                vtile[colL][rowL] = f2b(acc[c16][reg] + bias[(n0 & 255) + colL]);
            }
        __syncthreads();
        // V fragment layout: vf[b][h][m/64][ks][cg][tl][g][m8]
        int clocal = t >> 2, q4 = t & 3;
        int colg = (n0 & 255) + clocal;
        int hh = colg >> 5, dd = colg & 31;
        int bg = m0 >> 10;
        int m_loc = (m0 & 1023) + q4 * 8;
        int mt64 = m_loc >> 6, ks = (m_loc >> 5) & 1, gg = (m_loc >> 3) & 3;
        int cg = dd >> 4, tlv = dd & 15;
        ushort4 u0 = *(ushort4*)&vtile[clocal][q4 * 8];
        ushort4 u1 = *(ushort4*)&vtile[clocal][q4 * 8 + 4];
        unsigned short* dst = vTb
            + (((size_t)(bg * Hh + hh) * 16 + mt64) * 2048)
            + ((size_t)((ks * 2 + cg) * 16 + tlv) * 32) + gg * 8;
        *(ushort4*)dst = u0;
        *(ushort4*)(dst + 4) = u1;
    }
}

// ---------------- merged attention (blocks 0..255) + h1pre GEMM (256..511) ----------------
// R32: QROWS 16->32. With all loads coalesced (R29-R31), the remaining attn
// cost is load-instruction COUNT: 1 load per MFMA, 512MB of L2 K/V re-reads.
// Each wave now holds 2 q-fragments; every K-load feeds 2 QK MFMAs and every
// V-load feeds 2 PV MFMAs (qs loop inside the half; K/V hoisted above it;
// Ps reused serially per qs — wave-synchronous). K/V traffic and loads/MFMA
// halve. Avoids R22's failure modes: LDS 52KB (3 blk/CU), VGPR ~70 (<85 cap
// at launch_bounds(512,6)), 512-block grid (2/CU resident).
__global__ __launch_bounds__(512, 6) void attn_h1_k(
    const unsigned short* __restrict__ q, const unsigned short* __restrict__ k,
    const unsigned short* __restrict__ vT, const float* __restrict__ sph,
    unsigned short* __restrict__ op0,
    const unsigned short* __restrict__ xf, const unsigned short* __restrict__ WcatT,
    const float* __restrict__ x, unsigned short* __restrict__ h1preb,
    float* __restrict__ gsum, float* __restrict__ gsq)
{
    __shared__ float Sph[2][32][132];          // 33792 B
    __shared__ unsigned short Ps[Hh][16][72];  // 18432 B
    float* csum = (float*)&Ps[0][0][0];     // [256], aliased (gemm branch only)
    float* csq  = csum + 256;

    const int blk = blockIdx.x;
    const int t = threadIdx.x;
    const int wave = t >> 6;
    const int lane = t & 63;
    const int tl = lane & 15, g = lane >> 4;

    if (blk < 256) {
        // ---------- attention: 32 q-rows, full m-range, graph pinned to XCD ----------
        const int b  = blk & 7;             // graph == XCD (round-robin dispatch)
        const int n0 = (blk >> 3) * 32;     // 32 row-tiles per graph
        const int w  = wave;

        bf16x8 qf[2];
        #pragma unroll
        for (int qs = 0; qs < 2; ++qs)
            qf[qs] = ldb8(q + ((size_t)(b * Nn + n0 + qs * 16 + tl)) * Cc + w * DKh + g * 8);

        float lsum[2] = {0.f, 0.f};
        f32x4 oacc[2][2] = {};

        // coalesced fragment bases: lane offset = (tl*4+g)*16B within each 1KB tile
        const unsigned short* kfb = k + ((size_t)(b * 512 + w)) * 512 + tl * 32 + g * 8;
        const unsigned short* vfb = vT + ((size_t)(b * Hh + w) * 16) * 2048
                                     + (size_t)tl * 32 + g * 8;
        const float* sbase = sph + ((size_t)b * Nn + n0) * Nn;

        // prologue: stage sph tile 0 (32x128) into buffer 0; 512 thr x 2 float4
        {
            int r1 = t >> 4, c1 = (t & 15) * 8;
            const float* src = sbase + (size_t)r1 * Nn + c1;
            *(float4*)&Sph[0][r1][c1]     = *(const float4*)src;
            *(float4*)&Sph[0][r1][c1 + 4] = *(const float4*)(src + 4);
        }
        __syncthreads();

        int cur = 0;
        for (int it = 0; it < 8; ++it) {
            const int m0 = it * 128;
            // stage NEXT 32x128 tile into the other buffer
            if (it < 7) {
                int r1 = t >> 4, c1 = (t & 15) * 8;
                const float* src = sbase + (size_t)r1 * Nn + m0 + 128 + c1;
                *(float4*)&Sph[cur ^ 1][r1][c1]     = *(const float4*)src;
                *(float4*)&Sph[cur ^ 1][r1][c1 + 4] = *(const float4*)(src + 4);
            }

            #pragma unroll
            for (int half = 0; half < 2; ++half) {
                const int mh = m0 + half * 64;

                // K tile once, reused by both q-subtiles
                bf16x8 ka[4];
                #pragma unroll
                for (int mg = 0; mg < 4; ++mg)
                    ka[mg] = ldb8(kfb + (size_t)((mh >> 4) + mg) * 4096);
                // V tile once, reused by both q-subtiles
                const unsigned short* vtile64 = vfb + (size_t)(mh >> 6) * 2048;
                bf16x8 vb[2][2];
                #pragma unroll
                for (int ks = 0; ks < 2; ++ks)
                    #pragma unroll
                    for (int cg = 0; cg < 2; ++cg)
                        vb[ks][cg] = ldb8(vtile64 + (size_t)(half * 2 * 0 + ks * 2 + cg) * 512);

                #pragma unroll
                for (int qs = 0; qs < 2; ++qs) {
                    f32x4 st[4];
                    #pragma unroll
                    for (int mg = 0; mg < 4; ++mg) {
                        f32x4 z = {0.f, 0.f, 0.f, 0.f};
                        st[mg] = __builtin_amdgcn_mfma_f32_16x16x32_bf16(ka[mg], qf[qs], z, 0, 0, 0);
                    }

                    #pragma unroll
                    for (int mg = 0; mg < 4; ++mg) {
                        float4 sp = *(const float4*)&Sph[cur][qs * 16 + tl]
                                        [half * 64 + mg * 16 + g * 4];
                        float p0 = __builtin_amdgcn_exp2f(st[mg][0] * sp.x);
                        float p1 = __builtin_amdgcn_exp2f(st[mg][1] * sp.y);
                        float p2 = __builtin_amdgcn_exp2f(st[mg][2] * sp.z);
                        float p3 = __builtin_amdgcn_exp2f(st[mg][3] * sp.w);
                        lsum[qs] += (p0 + p1) + (p2 + p3);
                        ushort4 pk;
                        pk.x = f2b(p0); pk.y = f2b(p1); pk.z = f2b(p2); pk.w = f2b(p3);
                        *(ushort4*)&Ps[w][tl][mg * 16 + g * 4] = pk;
                    }

                    #pragma unroll
                    for (int ks = 0; ks < 2; ++ks) {
                        bf16x8 pa = ldb8(&Ps[w][tl][ks * 32 + g * 8]);
                        #pragma unroll
                        for (int cg = 0; cg < 2; ++cg)
                            oacc[qs][cg] = __builtin_amdgcn_mfma_f32_16x16x32_bf16(
                                pa, vb[ks][cg], oacc[qs][cg], 0, 0, 0);
                    }
                }
            }

            __syncthreads();   // staging writes visible; Sph[cur]/Ps reads complete
            cur ^= 1;
        }

        // full-row softmax denominators -> normalize O in-register.
        float* shl = (float*)&Ps[w][0][0]; // per-wave scratch (Ps dead now)
        #pragma unroll
        for (int qs = 0; qs < 2; ++qs) {
            float ls = lsum[qs];
            ls += __shfl_xor(ls, 16);
            ls += __shfl_xor(ls, 32);
            if (g == 0) shl[qs * 16 + tl] = ls;
        }
        // O written in fragment layout (KT=8): read coalesced by Wo GEMM.
        const size_t rt0 = (size_t)((b * Nn + n0) >> 4);
        #pragma unroll
        for (int qs = 0; qs < 2; ++qs)
            #pragma unroll
            for (int r = 0; r < 4; ++r) {
                float inv = 1.f / shl[qs * 16 + g * 4 + r];
                #pragma unroll
                for (int cg = 0; cg < 2; ++cg)
                    op0[((rt0 + qs) * 8 + w) * 512 + (g * 4 + r) * 32 + cg * 16 + tl]
                        = f2b(oacc[qs][cg][r] * inv);
            }
        return;
    }

    // ---------- h1pre GEMM: one 32x256 tile per block (frag A + frag B) ----------
    const int wrg = wave >> 2;              // 0..1 row group
    const int wcg = wave & 3;               // 0..3 col group (64 cols each)
    const int m0g = (blk - 256) * 32;
    const int N = Cc;

    if (t < 256) { csum[t] = 0.f; csq[t] = 0.f; }
    __syncthreads();

    f32x4 acc[4] = {};

    const unsigned short* a0 = xf + (size_t)((m0g >> 4) + wrg) * 16 * 512 + tl * 32 + g * 8;
    const unsigned short* bb = WcatT + (size_t)(wcg * 4) * 16 * 512 + tl * 32 + g * 8;

    for (int k0 = 0; k0 < 512; k0 += 32) {
        bf16x8 af = ldb8(a0 + (k0 >> 5) * 512);
        #pragma unroll
        for (int c16 = 0; c16 < 4; ++c16) {
            bf16x8 bf = ldb8(bb + ((size_t)c16 * 16 + (k0 >> 5)) * 512);
            acc[c16] = __builtin_amdgcn_mfma_f32_16x16x32_bf16(af, bf, acc[c16], 0, 0, 0);
        }
    }

    #pragma unroll
    for (int c16 = 0; c16 < 4; ++c16) {
        int col = wcg * 64 + c16 * 16 + tl;
        float ls = 0.f, lq = 0.f;
        #pragma unroll
        for (int reg = 0; reg < 4; ++reg) {
            int row = m0g + wrg * 16 + g * 4 + reg;
            size_t idx = (size_t)row * N + col;
            float v = acc[c16][reg] + x[idx];
            ls += v; lq += v * v;               // stats in fp32 (pre-rounding)
            h1preb[idx] = f2b(v);
        }
        atomicAdd(&csum[col], ls);
        atomicAdd(&csq[col],  lq);
    }
    __syncthreads();
    if (t < 256) {
        atomicAdd(&gsum[t], csum[t]);
        atomicAdd(&gsq[t],  csq[t]);
    }
}

// ---------------- mlp1: hid = relu(osb @ W1 + b1), frag A + frag B + frag out ----------------
__global__ __launch_bounds__(256, 4) void mlp1_k(
    const unsigned short* __restrict__ A,      // osb fragment, KT=8
    const unsigned short* __restrict__ WT,     // W1 fragment, KT=8, 512 cols
    const float* __restrict__ bias,
    unsigned short* __restrict__ outb)         // hid fragment, KT=16
{
    const int t = threadIdx.x;
    const int wave = t >> 6, lane = t & 63;
    const int tl = lane & 15, g = lane >> 4;
    const int wr = wave >> 1, wc = wave & 1;
    const int m0 = blockIdx.y * 32, n0 = blockIdx.x * 64;

    f32x4 acc[2] = {};

    const unsigned short* a0 = A  + (size_t)((m0 >> 4) + wr) * 8 * 512 + tl * 32 + g * 8;
    const unsigned short* b0 = WT + ((size_t)(n0 >> 4) + wc * 2) * 8 * 512 + tl * 32 + g * 8;
    const unsigned short* b1 = b0 + 8 * 512;

    for (int k0 = 0; k0 < 256; k0 += 32) {
        bf16x8 af  = ldb8(a0 + (k0 >> 5) * 512);
        bf16x8 bf0 = ldb8(b0 + (k0 >> 5) * 512), bf1 = ldb8(b1 + (k0 >> 5) * 512);
        acc[0] = __builtin_amdgcn_mfma_f32_16x16x32_bf16(af, bf0, acc[0], 0, 0, 0);
        acc[1] = __builtin_amdgcn_mfma_f32_16x16x32_bf16(af, bf1, acc[1], 0, 0, 0);
    }

    const size_t rtO = (size_t)(m0 >> 4) + wr;
    #pragma unroll
    for (int c16 = 0; c16 < 2; ++c16) {
        int col  = n0 + wc * 32 + c16 * 16 + tl;
        int ktO  = col >> 5;
        #pragma unroll
        for (int reg = 0; reg < 4; ++reg) {
            float v = fmaxf(acc[c16][reg] + bias[col], 0.f);
            outb[(rtO * 16 + ktO) * 512 + (g * 4 + reg) * 32 + (col & 31)] = f2b(v);
        }
    }
}

// ---------------- mlp2: out2 = hid @ W2 + b2 + osb, frag A/B/residual + BN3 stats ----------------
__global__ __launch_bounds__(256, 4) void mlp2_k(
    const unsigned short* __restrict__ A,      // hid fragment, KT=16
    const unsigned short* __restrict__ WT,     // W2 fragment, KT=16, 256 cols
    const float* __restrict__ bias,
    const unsigned short* __restrict__ addb,   // osb fragment, KT=8
    float* __restrict__ outf,                  // row-major fp32
    float* __restrict__ gsum, float* __restrict__ gsq)
{
    const int N = Cc;
    const int t = threadIdx.x;
    const int wave = t >> 6, lane = t & 63;
    const int tl = lane & 15, g = lane >> 4;
    const int wr = wave >> 1, wc = wave & 1;
    const int m0 = blockIdx.y * 32, n0 = blockIdx.x * 64;

    __shared__ float csum[64], csq[64];
    if (t < 64) { csum[t] = 0.f; csq[t] = 0.f; }
    __syncthreads();

    f32x4 acc[2] = {};

    const unsigned short* a0 = A  + (size_t)((m0 >> 4) + wr) * 16 * 512 + tl * 32 + g * 8;
    const unsigned short* b0 = WT + ((size_t)(n0 >> 4) + wc * 2) * 16 * 512 + tl * 32 + g * 8;
    const unsigned short* b1 = b0 + 16 * 512;

    for (int k0 = 0; k0 < 512; k0 += 32) {
        bf16x8 af  = ldb8(a0 + (k0 >> 5) * 512);
        bf16x8 bf0 = ldb8(b0 + (k0 >> 5) * 512), bf1 = ldb8(b1 + (k0 >> 5) * 512);
        acc[0] = __builtin_amdgcn_mfma_f32_16x16x32_bf16(af, bf0, acc[0], 0, 0, 0);
        acc[1] = __builtin_amdgcn_mfma_f32_16x16x32_bf16(af, bf1, acc[1], 0, 0, 0);
    }

    const size_t rtR = (size_t)(m0 >> 4) + wr;
    #pragma unroll
    for (int c16 = 0; c16 < 2; ++c16) {
        int colL = wc * 32 + c16 * 16 + tl;
        int col  = n0 + colL;
        int ktR  = col >> 5;
        float ls = 0.f, lq = 0.f;
        #pragma unroll
        for (int reg = 0; reg < 4; ++reg) {
            int row = m0 + wr * 16 + g * 4 + reg;
            float v = acc[c16][reg] + bias[col]
                    + b2f(addb[(rtR * 8 + ktR) * 512 + (g * 4 + reg) * 32 + (col & 31)]);
            ls += v; lq += v * v;
            outf[(size_t)row * N + col] = v;
        }
        atomicAdd(&csum[colL], ls); atomicAdd(&csq[colL], lq);
    }
    __syncthreads();
    if (t < 64) {
        atomicAdd(&gsum[n0 + t], csum[t]);
        atomicAdd(&gsq[n0 + t],  csq[t]);
    }
}

// ---------------- Wo GEMM (A = op0 fragment) + fp32 residual + BN2 stats ----------------
__global__ __launch_bounds__(256, 4) void gemm_attnA_k(
    const unsigned short* __restrict__ op0,    // fragment, KT=8
    const unsigned short* __restrict__ WT, const float* __restrict__ bias,
    const float* __restrict__ add1, unsigned short* __restrict__ h2preb,
    float* __restrict__ gsum, float* __restrict__ gsq)
{
    const int N = Cc;
    const int t = threadIdx.x;
    const int wave = t >> 6, lane = t & 63;
    const int tl = lane & 15, g = lane >> 4;
    const int wr = wave >> 1, wc = wave & 1;
    const int m0 = blockIdx.y * 32, n0 = blockIdx.x * 64;

    __shared__ float csum[64], csq[64];
    if (t < 64) { csum[t] = 0.f; csq[t] = 0.f; }
    __syncthreads();

    f32x4 acc[2] = {};

    const unsigned short* a0b = op0 + (size_t)((m0 >> 4) + wr) * 8 * 512 + tl * 32 + g * 8;
    const unsigned short* b0 = WT + ((size_t)(n0 >> 4) + wc * 2) * 8 * 512 + tl * 32 + g * 8;
    const unsigned short* b1 = b0 + 8 * 512;

    for (int k0 = 0; k0 < 256; k0 += 32) {
        bf16x8 af  = ldb8(a0b + (k0 >> 5) * 512);
        bf16x8 bf0 = ldb8(b0 + (k0 >> 5) * 512), bf1 = ldb8(b1 + (k0 >> 5) * 512);
        acc[0] = __builtin_amdgcn_mfma_f32_16x16x32_bf16(af, bf0, acc[0], 0, 0, 0);
        acc[1] = __builtin_amdgcn_mfma_f32_16x16x32_bf16(af, bf1, acc[1], 0, 0, 0);
    }

    #pragma unroll
    for (int c16 = 0; c16 < 2; ++c16) {
        int colL = wc * 32 + c16 * 16 + tl;
        int col  = n0 + colL;
        float ls = 0.f, lq = 0.f;
        #pragma unroll
        for (int reg = 0; reg < 4; ++reg) {
            int row = m0 + wr * 16 + g * 4 + reg;
            float v = acc[c16][reg] + bias[col];
            size_t idx = (size_t)row * N + col;
            v += add1[idx];
            ls += v; lq += v * v;               // stats in fp32 (pre-rounding)
            h2preb[idx] = f2b(v);
        }
        atomicAdd(&csum[colL], ls); atomicAdd(&csq[colL], lq);
    }
    __syncthreads();
    if (t < 64) {
        atomicAdd(&gsum[n0 + t], csum[t]);
        atomicAdd(&gsq[n0 + t],  csq[t]);
    }
}

// ---------------- BN apply (single, float4) ----------------
__global__ __launch_bounds__(256) void bn_apply_k(
    const float* __restrict__ h, const float* __restrict__ gsum,
    const float* __restrict__ gsq, const float* __restrict__ gamma,
    const float* __restrict__ beta, float* __restrict__ outf)
{
    size_t i4 = ((size_t)blockIdx.x * 256 + threadIdx.x) * 4;
    int ch = (int)(i4 & (Cc - 1));
    float4 hv = *(const float4*)(h + i4);
    float4 sm = *(const float4*)(gsum + ch);
    float4 sq = *(const float4*)(gsq + ch);
    float4 ga = *(const float4*)(gamma + ch);
    float4 be = *(const float4*)(beta + ch);
    float4 o;
    {
        float m = sm.x * (1.f / BNn), var = sq.x * (1.f / BNn) - m * m;
        o.x = (hv.x - m) * rsqrtf(var + EPSV) * ga.x + be.x;
    }
    {
        float m = sm.y * (1.f / BNn), var = sq.y * (1.f / BNn) - m * m;
        o.y = (hv.y - m) * rsqrtf(var + EPSV) * ga.y + be.y;
    }
    {
        float m = sm.z * (1.f / BNn), var = sq.z * (1.f / BNn) - m * m;
        o.z = (hv.z - m) * rsqrtf(var + EPSV) * ga.z + be.z;
    }
    {
        float m = sm.w * (1.f / BNn), var = sq.w * (1.f / BNn) - m * m;
        o.w = (hv.w - m) * rsqrtf(var + EPSV) * ga.w + be.w;
    }
    *(float4*)(outf + i4) = o;
}

// ---------------- fused BN1+BN2 apply -> osb in FRAGMENT layout ----------------
__global__ __launch_bounds__(256) void bn_apply12_k(
    const unsigned short* __restrict__ h1preb, const unsigned short* __restrict__ h2preb,
    const float* __restrict__ stats,
    const float* __restrict__ g1, const float* __restrict__ be1,
    const float* __restrict__ g2, const float* __restrict__ be2,
    unsigned short* __restrict__ outb)         // osb fragment, KT=8
{
    size_t i4 = ((size_t)blockIdx.x * 256 + threadIdx.x) * 4;
    int ch = (int)(i4 & (Cc - 1));
    ushort4 u1 = *(const ushort4*)(h1preb + i4);
    ushort4 u2 = *(const ushort4*)(h2preb + i4);
    float4 s1m = *(const float4*)(stats + ch);
    float4 s1q = *(const float4*)(stats + 256 + ch);
    float4 s2m = *(const float4*)(stats + 512 + ch);
    float4 s2q = *(const float4*)(stats + 768 + ch);
    float4 G1 = *(const float4*)(g1 + ch),  B1 = *(const float4*)(be1 + ch);
    float4 G2 = *(const float4*)(g2 + ch),  B2 = *(const float4*)(be2 + ch);
    ushort4 pk;
    #define BN12C(comp, ucomp) { \
        float m1 = s1m.comp * (1.f / BNn), v1 = s1q.comp * (1.f / BNn) - m1 * m1; \
        float m2 = s2m.comp * (1.f / BNn), v2 = s2q.comp * (1.f / BNn) - m2 * m2; \
        float o = (b2f(u1.ucomp) - m1) * rsqrtf(v1 + EPSV) * G1.comp + B1.comp \
                + (b2f(u2.ucomp) - m2) * rsqrtf(v2 + EPSV) * G2.comp + B2.comp; \
        pk.ucomp = f2b(o); }
    BN12C(x, x) BN12C(y, y) BN12C(z, z) BN12C(w, w)
    #undef BN12C
    int row = (int)(i4 >> 8), col = ch;        // col 4-aligned, stays in one 32-tile
    *(ushort4*)(outb + ((size_t)(row >> 4) * 8 + (col >> 5)) * 512
                + (row & 15) * 32 + (col & 31)) = pk;
}

// ---------------- launch ----------------
extern "C" void kernel_launch(void* const* d_in, const int* in_sizes, int n_in,
                              void* d_out, int out_size, void* d_ws, size_t ws_size,
                              hipStream_t stream)
{
    const float* x   = (const float*)d_in[0];
    const int*   ei  = (const int*)  d_in[1];
    const float* sph = (const float*)d_in[2];
    const float* Wr  = (const float*)d_in[3];
    const float* Wn  = (const float*)d_in[4];
    const float* Wq  = (const float*)d_in[5];
    const float* bq  = (const float*)d_in[6];
    const float* Wk  = (const float*)d_in[7];
    const float* bk  = (const float*)d_in[8];
    const float* Wv  = (const float*)d_in[9];
    const float* bv  = (const float*)d_in[10];
    const float* Wo  = (const float*)d_in[11];
    const float* bo  = (const float*)d_in[12];
    const float* W1  = (const float*)d_in[13];
    const float* b1  = (const float*)d_in[14];
    const float* W2  = (const float*)d_in[15];
    const float* b2  = (const float*)d_in[16];
    const float* g1  = (const float*)d_in[17];
    const float* be1 = (const float*)d_in[18];
    const float* g2  = (const float*)d_in[19];
    const float* be2 = (const float*)d_in[20];
    const float* g3  = (const float*)d_in[21];
    const float* be3 = (const float*)d_in[22];
    float* out = (float*)d_out;

    const size_t SL = (size_t)BNn * Cc;  // 2M elements

    float* ws = (float*)d_ws;
    float* s1 = ws;                  // op0b (bf16 fragment, 4MB)
    float* s2 = s1 + SL;             // h1preb (bf16) then out2 (fp32)
    float* s3 = s2 + SL;             // h2preb (bf16)

    int*   deg      = (int*)(s3 + SL);          // 8192
    float* statsAll = (float*)(deg + 8192);     // 1536
    int*   rowst    = (int*)(statsAll + 1536);  // 8192 (+pad)
    int*   cursor   = rowst + 8256;             // 8192
    int*   eidx     = cursor + 8192;            // 131072

    unsigned short* xf  = (unsigned short*)(eidx + 131072); // fragment; reused as hid
    unsigned short* qb  = xf + 2 * SL;
    unsigned short* kb  = qb + SL;                           // reused as osb (fragment)
    unsigned short* vTb = kb + SL;
    unsigned short* osb = kb;
    unsigned short* hid = xf;

    unsigned short* WcatT = vTb + SL;         // fragment
    unsigned short* WqT   = WcatT + 131072;   // fragment [768 cols][256 K]
    unsigned short* WkT   = WqT + 65536;
    unsigned short* WvT   = WkT + 65536;
    unsigned short* WoT   = WvT + 65536;
    unsigned short* W1T   = WoT + 65536;
    unsigned short* W2T   = W1T + 131072;
    unsigned short* xlo   = W2T + 131072;     // row-major bf16 x copy [8192][256]
    unsigned short* op0b   = (unsigned short*)s1;
    unsigned short* h1preb = (unsigned short*)s2;   // 4MB of s2; dead before out2
    unsigned short* h2preb = (unsigned short*)s3;

    dim3 gN256(4, 256);
    dim3 gN512(8, 256);

    const float QSCALE = 0.17677669529663687f * 1.4426950408889634f;

    // 1) zero deg + all BN stats in one memset
    hipMemsetAsync(deg, 0, (8192 + 1536) * sizeof(float), stream);
    // 2) fused converts + histogram (fragment weight layouts + xlo copy)
    prep_k<<<5120, 256, 0, stream>>>(x, xf, xlo, Wr, Wn, Wq, Wk, Wv, Wo, W1, W2,
                                     WcatT, WqT, WkT, WvT, WoT, W1T, W2T, ei, deg);
    // 3-4) CSR scan / place
    scan_k<<<1, 256, 0, stream>>>(deg, rowst, cursor);
    place_k<<<Ee / 256, 256, 0, stream>>>(ei, cursor, eidx);
    // 5) gather (xlo -> xf hi kts) || QKV GEMM (frag A/B + frag K/V out)
    gather_qkv_k<<<5120, 256, 0, stream>>>(xlo, rowst, deg, eidx, xf,
                                           WqT, bq, bk, bv, qb, kb, vTb, QSCALE);
    // 6) attention (32 q-rows, K/V reuse x2) || h1pre GEMM — 512 blocks
    attn_h1_k<<<512, 512, 0, stream>>>(qb, kb, vTb, sph, op0b,
                                       xf, WcatT, x, h1preb,
                                       statsAll, statsAll + 256);
    // 7) h2pre = O @ Wo + bo + x -> bf16, + BN2 stats (frag A)
    gemm_attnA_k<<<gN256, 256, 0, stream>>>(op0b, WoT, bo, x,
                                            h2preb, statsAll + 512, statsAll + 768);
    // 8) osb(frag) = bn1(h1pre) + bn2(h2pre)
    bn_apply12_k<<<(int)(SL / 1024), 256, 0, stream>>>(h1preb, h2preb, statsAll,
                                                       g1, be1, g2, be2, osb);
    // 9) hid(frag) = relu(osb @ W1 + b1)
    mlp1_k<<<gN512, 256, 0, stream>>>(osb, W1T, b1, hid);
    // 10) out2 = hid @ W2 + b2 + osb(frag residual) -> s2 fp32, + BN3 stats
    mlp2_k<<<gN256, 256, 0, stream>>>(hid, W2T, b2, osb, s2,
                                      statsAll + 1024, statsAll + 1280);
    // 11) d_out = BN3(out2)
    bn_apply_k<<<(int)(SL / 1024), 256, 0, stream>>>(s2, statsAll + 1024,
                                                     statsAll + 1280, g3, be3, out);
}

// Round 18
// 280.376 us; speedup vs baseline: 1.1518x; 1.1518x over previous
//
#include <hip/hip_runtime.h>
#include <hip/hip_bf16.h>

// ---------------- problem constants ----------------
constexpr int Bg  = 8;       // graphs
constexpr int Nn  = 1024;    // nodes per graph
constexpr int Cc  = 256;     // channels
constexpr int Hh  = 8;       // heads
constexpr int DKh = 32;      // head dim
constexpr int Ee  = 131072;  // edges
constexpr int BNn = Bg * Nn; // 8192 total nodes
#define EPSV 1e-5f

// R33 = R31 (verified best, 285.2us). R32's QROWS=32 attempt spilled to
// scratch (WRITE_SIZE 18->161MB, the R23 signature) and is reverted.
// Fragment formula everywhere (R29-R31 validated; KT = K/32):
//   idx(row,col) = ((row>>4)*KT + (col>>5))*512 + (row&15)*32 + (col&31)

typedef __attribute__((ext_vector_type(8))) short bf16x8;
typedef __attribute__((ext_vector_type(4))) float f32x4;

static __device__ __forceinline__ unsigned short f2b(float v) {
    __hip_bfloat16 h = __float2bfloat16(v);
    return __builtin_bit_cast(unsigned short, h);
}
static __device__ __forceinline__ float b2f(unsigned short u) {
    unsigned int x = ((unsigned int)u) << 16;
    return __builtin_bit_cast(float, x);
}
static __device__ __forceinline__ bf16x8 ldb8(const unsigned short* p) {
    return *(const bf16x8*)p;
}

// ---------------- fused prep: xconv + wconv + hist ----------------
__global__ __launch_bounds__(256) void prep_k(
    const float* __restrict__ x, unsigned short* __restrict__ xf,
    unsigned short* __restrict__ xlo,
    const float* __restrict__ Wr, const float* __restrict__ Wn,
    const float* __restrict__ Wq, const float* __restrict__ Wk,
    const float* __restrict__ Wv, const float* __restrict__ Wo,
    const float* __restrict__ W1, const float* __restrict__ W2,
    unsigned short* __restrict__ WcatT,
    unsigned short* __restrict__ WqT, unsigned short* __restrict__ WkT,
    unsigned short* __restrict__ WvT, unsigned short* __restrict__ WoT,
    unsigned short* __restrict__ W1T, unsigned short* __restrict__ W2T,
    const int* __restrict__ ei, int* __restrict__ deg)
{
    int blk = blockIdx.x;
    if (blk < 2048) {
        int i = (blk * 256 + threadIdx.x) * 4;
        float4 v = *(const float4*)(x + i);
        int r = i >> 8, c = i & 255;
        ushort4 pk;
        pk.x = f2b(v.x); pk.y = f2b(v.y); pk.z = f2b(v.z); pk.w = f2b(v.w);
        *(ushort4*)(xlo + (size_t)r * 256 + c) = pk;       // row-major (gather src)
        *(ushort4*)(xf + ((size_t)(r >> 4) * 16 + (c >> 5)) * 512
                    + (r & 15) * 32 + (c & 31)) = pk;      // fragment (GEMM A)
    } else if (blk < 4608) {
        int idx = (blk - 2048) * 256 + threadIdx.x;
        if (idx < 131072) {                      // WcatT frag [n/16][k/32][16][32], K=512
            int n = idx >> 9, k = idx & 511;
            float v = (k < 256) ? Wr[k * 256 + n] : Wn[(k - 256) * 256 + n];
            WcatT[((size_t)(n >> 4) * 16 + (k >> 5)) * 512 + (n & 15) * 32 + (k & 31)] = f2b(v);
        } else if (idx < 393216) {               // q,k,v,o frag, K=256
            int l = idx - 131072;
            int wsel = l >> 16; l &= 65535;
            int n = l >> 8, kk = l & 255;
            const float* S = wsel == 0 ? Wq : wsel == 1 ? Wk : wsel == 2 ? Wv : Wo;
            unsigned short* D = wsel == 0 ? WqT : wsel == 1 ? WkT : wsel == 2 ? WvT : WoT;
            D[((size_t)(n >> 4) * 8 + (kk >> 5)) * 512 + (n & 15) * 32 + (kk & 31)]
                = f2b(S[kk * 256 + n]);
        } else if (idx < 524288) {               // W1 frag [512 cols], K=256
            int l = idx - 393216;
            int n = l >> 8, kk = l & 255;
            W1T[((size_t)(n >> 4) * 8 + (kk >> 5)) * 512 + (n & 15) * 32 + (kk & 31)]
                = f2b(W1[kk * 512 + n]);
        } else {                                 // W2 frag [256 cols], K=512
            int l = idx - 524288;
            int n = l >> 9, kk = l & 511;
            W2T[((size_t)(n >> 4) * 16 + (kk >> 5)) * 512 + (n & 15) * 32 + (kk & 31)]
                = f2b(W2[kk * 256 + n]);
        }
    } else {
        int e = (blk - 4608) * 256 + threadIdx.x;
        atomicAdd(&deg[ei[Ee + e]], 1);
    }
}

// ---------------- CSR scan (coalesced, interleaved buckets) ----------------
__global__ __launch_bounds__(256) void scan_k(
    const int* __restrict__ deg, int* __restrict__ rowst, int* __restrict__ cursor)
{
    __shared__ int partial[256];
    int t = threadIdx.x;
    int local[32];
    int s = 0;
    #pragma unroll
    for (int i = 0; i < 32; ++i) { local[i] = deg[i * 256 + t]; s += local[i]; }
    partial[t] = s;
    __syncthreads();
    for (int off = 1; off < 256; off <<= 1) {
        int v = (t >= off) ? partial[t - off] : 0;
        __syncthreads();
        partial[t] += v;
        __syncthreads();
    }
    int base = partial[t] - s;
    #pragma unroll
    for (int i = 0; i < 32; ++i) {
        int n = i * 256 + t;
        rowst[n] = base;
        cursor[n] = base;
        base += local[i];
    }
}

__global__ __launch_bounds__(256) void place_k(
    const int* __restrict__ ei, int* __restrict__ cursor, int* __restrict__ eidx)
{
    int e = blockIdx.x * 256 + threadIdx.x;
    int s = ei[e], d = ei[Ee + e];
    int pos = atomicAdd(&cursor[d], 1);
    eidx[pos] = s;
}

// ---------------- merged gather (blocks 0..2047) + QKV GEMM (2048..5119) ----------------
__global__ __launch_bounds__(256, 4) void gather_qkv_k(
    const unsigned short* __restrict__ xlo, const int* __restrict__ rowst,
    const int* __restrict__ deg, const int* __restrict__ eidx,
    unsigned short* __restrict__ xf,
    const unsigned short* __restrict__ WT,
    const float* __restrict__ bq, const float* __restrict__ bk,
    const float* __restrict__ bv,
    unsigned short* __restrict__ qb, unsigned short* __restrict__ kb,
    unsigned short* __restrict__ vTb, float qscale)
{
    __shared__ unsigned short vtile[64][40];
    int blk = blockIdx.x;

    if (blk < 2048) {
        // gather: 4 nodes per block, one 64-lane wave each (bf16 row-major src)
        int n = blk * 4 + (threadIdx.x >> 6);
        int c4 = (threadIdx.x & 63) * 4;
        int b0 = rowst[n], d = deg[n];
        float4 acc = {0.f, 0.f, 0.f, 0.f};
        int i = 0;
        for (; i + 4 <= d; i += 4) {
            int s0 = eidx[b0 + i], s1 = eidx[b0 + i + 1];
            int s2 = eidx[b0 + i + 2], s3 = eidx[b0 + i + 3];
            ushort4 a0 = *(const ushort4*)(xlo + (size_t)s0 * 256 + c4);
            ushort4 a1 = *(const ushort4*)(xlo + (size_t)s1 * 256 + c4);
            ushort4 a2 = *(const ushort4*)(xlo + (size_t)s2 * 256 + c4);
            ushort4 a3 = *(const ushort4*)(xlo + (size_t)s3 * 256 + c4);
            acc.x += (b2f(a0.x) + b2f(a1.x)) + (b2f(a2.x) + b2f(a3.x));
            acc.y += (b2f(a0.y) + b2f(a1.y)) + (b2f(a2.y) + b2f(a3.y));
            acc.z += (b2f(a0.z) + b2f(a1.z)) + (b2f(a2.z) + b2f(a3.z));
            acc.w += (b2f(a0.w) + b2f(a1.w)) + (b2f(a2.w) + b2f(a3.w));
        }
        for (; i < d; ++i) {
            int s = eidx[b0 + i];
            ushort4 a = *(const ushort4*)(xlo + (size_t)s * 256 + c4);
            acc.x += b2f(a.x); acc.y += b2f(a.y);
            acc.z += b2f(a.z); acc.w += b2f(a.w);
        }
        ushort4 pk;
        pk.x = f2b(acc.x); pk.y = f2b(acc.y); pk.z = f2b(acc.z); pk.w = f2b(acc.w);
        int cg2 = 256 + c4;                    // agg occupies cols 256..511 of xf
        *(ushort4*)(xf + ((size_t)(n >> 4) * 16 + (cg2 >> 5)) * 512
                    + (n & 15) * 32 + (cg2 & 31)) = pk;
        return;
    }

    // QKV GEMM, N=768 = [q|k|v]; fragment A (xf kts 0..7) + fragment B
    int qblk = blk - 2048;
    const int n0 = (qblk % 12) * 64;
    const int m0 = (qblk / 12) * 32;
    const int t = threadIdx.x;
    const int wave = t >> 6, lane = t & 63;
    const int tl = lane & 15, g = lane >> 4;
    const int wr = wave >> 1, wc = wave & 1;
    const int which = n0 >> 8;               // 0:q 1:k 2:v

    f32x4 acc[2] = {};

    const unsigned short* a0 = xf + (size_t)((m0 >> 4) + wr) * 16 * 512 + tl * 32 + g * 8;
    const unsigned short* b0 = WT + ((size_t)(n0 >> 4) + wc * 2) * 8 * 512 + tl * 32 + g * 8;
    const unsigned short* b1 = b0 + 8 * 512;

    for (int k0 = 0; k0 < 256; k0 += 32) {
        bf16x8 af  = ldb8(a0 + (k0 >> 5) * 512);
        bf16x8 bf0 = ldb8(b0 + (k0 >> 5) * 512), bf1 = ldb8(b1 + (k0 >> 5) * 512);
        acc[0] = __builtin_amdgcn_mfma_f32_16x16x32_bf16(af, bf0, acc[0], 0, 0, 0);
        acc[1] = __builtin_amdgcn_mfma_f32_16x16x32_bf16(af, bf1, acc[1], 0, 0, 0);
    }

    const float* bias = which == 0 ? bq : which == 1 ? bk : bv;
    const float sc = which == 0 ? qscale : 1.f;

    if (which == 0) {
        #pragma unroll
        for (int c16 = 0; c16 < 2; ++c16)
            #pragma unroll
            for (int reg = 0; reg < 4; ++reg) {
                int row = m0 + wr * 16 + g * 4 + reg;
                int col = (n0 & 255) + wc * 32 + c16 * 16 + tl;
                qb[(size_t)row * Cc + col] = f2b((acc[c16][reg] + bias[col]) * sc);
            }
    } else if (which == 1) {
        // K fragment layout: kf[(row>>4)*8 + (col>>5)][row&15][col&31]
        #pragma unroll
        for (int c16 = 0; c16 < 2; ++c16)
            #pragma unroll
            for (int reg = 0; reg < 4; ++reg) {
                int row = m0 + wr * 16 + g * 4 + reg;
                int col = (n0 & 255) + wc * 32 + c16 * 16 + tl;
                kb[((size_t)(row >> 4) * 8 + (col >> 5)) * 512
                   + (row & 15) * 32 + (col & 31)] = f2b(acc[c16][reg] + bias[col]);
            }
    } else {
        #pragma unroll
        for (int c16 = 0; c16 < 2; ++c16)
            #pragma unroll
            for (int reg = 0; reg < 4; ++reg) {
                int colL = wc * 32 + c16 * 16 + tl;
                int rowL = wr * 16 + g * 4 + reg;
                vtile[colL][rowL] = f2b(acc[c16][reg] + bias[(n0 & 255) + colL]);
            }
        __syncthreads();
        // V fragment layout: vf[b][h][m/64][ks][cg][tl][g][m8]
        int clocal = t >> 2, q4 = t & 3;
        int colg = (n0 & 255) + clocal;
        int hh = colg >> 5, dd = colg & 31;
        int bg = m0 >> 10;
        int m_loc = (m0 & 1023) + q4 * 8;
        int mt64 = m_loc >> 6, ks = (m_loc >> 5) & 1, gg = (m_loc >> 3) & 3;
        int cg = dd >> 4, tlv = dd & 15;
        ushort4 u0 = *(ushort4*)&vtile[clocal][q4 * 8];
        ushort4 u1 = *(ushort4*)&vtile[clocal][q4 * 8 + 4];
        unsigned short* dst = vTb
            + (((size_t)(bg * Hh + hh) * 16 + mt64) * 2048)
            + ((size_t)((ks * 2 + cg) * 16 + tlv) * 32) + gg * 8;
        *(ushort4*)dst = u0;
        *(ushort4*)(dst + 4) = u1;
    }
}

// ---------------- merged attention (blocks 0..511) + h1pre GEMM (512..767) ----------------
__global__ __launch_bounds__(512, 8) void attn_h1_k(
    const unsigned short* __restrict__ q, const unsigned short* __restrict__ k,
    const unsigned short* __restrict__ vT, const float* __restrict__ sph,
    unsigned short* __restrict__ op0,
    const unsigned short* __restrict__ xf, const unsigned short* __restrict__ WcatT,
    const float* __restrict__ x, unsigned short* __restrict__ h1preb,
    float* __restrict__ gsum, float* __restrict__ gsq)
{
    __shared__ float Sph[2][16][132];          // 16896 B
    __shared__ unsigned short Ps[Hh][16][72];  // 18432 B
    float* csum = (float*)&Ps[0][0][0];     // [256], aliased (gemm branch only)
    float* csq  = csum + 256;

    const int blk = blockIdx.x;
    const int t = threadIdx.x;
    const int wave = t >> 6;
    const int lane = t & 63;
    const int tl = lane & 15, g = lane >> 4;

    if (blk < 512) {
        // ---------- attention: 16 q-rows, full m-range, graph pinned to XCD ----------
        const int b  = blk & 7;             // graph == XCD (round-robin dispatch)
        const int n0 = (blk >> 3) * 16;     // 64 row-tiles per graph
        const int w  = wave;

        bf16x8 qf = ldb8(q + ((size_t)(b * Nn + n0 + tl)) * Cc + w * DKh + g * 8);

        float lsum = 0.f;
        f32x4 oacc[2] = {};

        // coalesced fragment bases: lane offset = (tl*4+g)*16B within each 1KB tile
        const unsigned short* kfb = k + ((size_t)(b * 512 + w)) * 512 + tl * 32 + g * 8;
        const unsigned short* vfb = vT + ((size_t)(b * Hh + w) * 16) * 2048
                                     + (size_t)tl * 32 + g * 8;
        const float* sbase = sph + ((size_t)b * Nn + n0) * Nn;

        // prologue: stage sph tile 0 (16x128) into buffer 0; 256 thr x 2 float4
        if (t < 256) {
            int r1 = t >> 4, c1 = (t & 15) * 8;
            const float* src = sbase + (size_t)r1 * Nn + c1;
            *(float4*)&Sph[0][r1][c1]     = *(const float4*)src;
            *(float4*)&Sph[0][r1][c1 + 4] = *(const float4*)(src + 4);
        }
        __syncthreads();

        int cur = 0;
        for (int it = 0; it < 8; ++it) {
            const int m0 = it * 128;
            // stage NEXT 16x128 tile into the other buffer
            if (it < 7 && t < 256) {
                int r1 = t >> 4, c1 = (t & 15) * 8;
                const float* src = sbase + (size_t)r1 * Nn + m0 + 128 + c1;
                *(float4*)&Sph[cur ^ 1][r1][c1]     = *(const float4*)src;
                *(float4*)&Sph[cur ^ 1][r1][c1 + 4] = *(const float4*)(src + 4);
            }

            #pragma unroll
            for (int half = 0; half < 2; ++half) {
                const int mh = m0 + half * 64;

                f32x4 st[4];
                #pragma unroll
                for (int mg = 0; mg < 4; ++mg) {
                    bf16x8 ka = ldb8(kfb + (size_t)((mh >> 4) + mg) * 4096);
                    f32x4 z = {0.f, 0.f, 0.f, 0.f};
                    st[mg] = __builtin_amdgcn_mfma_f32_16x16x32_bf16(ka, qf, z, 0, 0, 0);
                }

                #pragma unroll
                for (int mg = 0; mg < 4; ++mg) {
                    float4 sp = *(const float4*)&Sph[cur][tl][half * 64 + mg * 16 + g * 4];
                    float p0 = __builtin_amdgcn_exp2f(st[mg][0] * sp.x);
                    float p1 = __builtin_amdgcn_exp2f(st[mg][1] * sp.y);
                    float p2 = __builtin_amdgcn_exp2f(st[mg][2] * sp.z);
                    float p3 = __builtin_amdgcn_exp2f(st[mg][3] * sp.w);
                    lsum += (p0 + p1) + (p2 + p3);
                    ushort4 pk;
                    pk.x = f2b(p0); pk.y = f2b(p1); pk.z = f2b(p2); pk.w = f2b(p3);
                    *(ushort4*)&Ps[w][tl][mg * 16 + g * 4] = pk;
                }

                const unsigned short* vtile64 = vfb + (size_t)(mh >> 6) * 2048;
                #pragma unroll
                for (int ks = 0; ks < 2; ++ks) {
                    bf16x8 pa = ldb8(&Ps[w][tl][ks * 32 + g * 8]);
                    #pragma unroll
                    for (int cg = 0; cg < 2; ++cg) {
                        bf16x8 vb = ldb8(vtile64 + (size_t)(ks * 2 + cg) * 512);
                        oacc[cg] = __builtin_amdgcn_mfma_f32_16x16x32_bf16(pa, vb, oacc[cg], 0, 0, 0);
                    }
                }
            }

            __syncthreads();   // staging writes visible; Sph[cur]/Ps reads complete
            cur ^= 1;
        }

        // full-row softmax denominator -> normalize O in-register.
        lsum += __shfl_xor(lsum, 16);
        lsum += __shfl_xor(lsum, 32);      // every lane: sum for q-row tl
        float* shl = (float*)&Ps[w][0][0]; // per-wave scratch (Ps dead now)
        if (g == 0) shl[tl] = lsum;        // wave-local write->read, no barrier
        // O written in fragment layout (KT=8): read coalesced by Wo GEMM.
        const size_t rt = (size_t)((b * Nn + n0) >> 4);
        #pragma unroll
        for (int r = 0; r < 4; ++r) {
            float inv = 1.f / shl[g * 4 + r];   // O row = g*4+r
            #pragma unroll
            for (int cg = 0; cg < 2; ++cg)
                op0[(rt * 8 + w) * 512 + (g * 4 + r) * 32 + cg * 16 + tl]
                    = f2b(oacc[cg][r] * inv);
        }
        return;
    }

    // ---------- h1pre GEMM: one 32x256 tile per block (frag A + frag B) ----------
    const int wrg = wave >> 2;              // 0..1 row group
    const int wcg = wave & 3;               // 0..3 col group (64 cols each)
    const int m0g = (blk - 512) * 32;
    const int N = Cc;

    if (t < 256) { csum[t] = 0.f; csq[t] = 0.f; }
    __syncthreads();

    f32x4 acc[4] = {};

    const unsigned short* a0 = xf + (size_t)((m0g >> 4) + wrg) * 16 * 512 + tl * 32 + g * 8;
    const unsigned short* bb = WcatT + (size_t)(wcg * 4) * 16 * 512 + tl * 32 + g * 8;

    for (int k0 = 0; k0 < 512; k0 += 32) {
        bf16x8 af = ldb8(a0 + (k0 >> 5) * 512);
        #pragma unroll
        for (int c16 = 0; c16 < 4; ++c16) {
            bf16x8 bf = ldb8(bb + ((size_t)c16 * 16 + (k0 >> 5)) * 512);
            acc[c16] = __builtin_amdgcn_mfma_f32_16x16x32_bf16(af, bf, acc[c16], 0, 0, 0);
        }
    }

    #pragma unroll
    for (int c16 = 0; c16 < 4; ++c16) {
        int col = wcg * 64 + c16 * 16 + tl;
        float ls = 0.f, lq = 0.f;
        #pragma unroll
        for (int reg = 0; reg < 4; ++reg) {
            int row = m0g + wrg * 16 + g * 4 + reg;
            size_t idx = (size_t)row * N + col;
            float v = acc[c16][reg] + x[idx];
            ls += v; lq += v * v;               // stats in fp32 (pre-rounding)
            h1preb[idx] = f2b(v);
        }
        atomicAdd(&csum[col], ls);
        atomicAdd(&csq[col],  lq);
    }
    __syncthreads();
    if (t < 256) {
        atomicAdd(&gsum[t], csum[t]);
        atomicAdd(&gsq[t],  csq[t]);
    }
}

// ---------------- mlp1: hid = relu(osb @ W1 + b1), frag A + frag B + frag out ----------------
__global__ __launch_bounds__(256, 4) void mlp1_k(
    const unsigned short* __restrict__ A,      // osb fragment, KT=8
    const unsigned short* __restrict__ WT,     // W1 fragment, KT=8, 512 cols
    const float* __restrict__ bias,
    unsigned short* __restrict__ outb)         // hid fragment, KT=16
{
    const int t = threadIdx.x;
    const int wave = t >> 6, lane = t & 63;
    const int tl = lane & 15, g = lane >> 4;
    const int wr = wave >> 1, wc = wave & 1;
    const int m0 = blockIdx.y * 32, n0 = blockIdx.x * 64;

    f32x4 acc[2] = {};

    const unsigned short* a0 = A  + (size_t)((m0 >> 4) + wr) * 8 * 512 + tl * 32 + g * 8;
    const unsigned short* b0 = WT + ((size_t)(n0 >> 4) + wc * 2) * 8 * 512 + tl * 32 + g * 8;
    const unsigned short* b1 = b0 + 8 * 512;

    for (int k0 = 0; k0 < 256; k0 += 32) {
        bf16x8 af  = ldb8(a0 + (k0 >> 5) * 512);
        bf16x8 bf0 = ldb8(b0 + (k0 >> 5) * 512), bf1 = ldb8(b1 + (k0 >> 5) * 512);
        acc[0] = __builtin_amdgcn_mfma_f32_16x16x32_bf16(af, bf0, acc[0], 0, 0, 0);
        acc[1] = __builtin_amdgcn_mfma_f32_16x16x32_bf16(af, bf1, acc[1], 0, 0, 0);
    }

    const size_t rtO = (size_t)(m0 >> 4) + wr;
    #pragma unroll
    for (int c16 = 0; c16 < 2; ++c16) {
        int col  = n0 + wc * 32 + c16 * 16 + tl;
        int ktO  = col >> 5;
        #pragma unroll
        for (int reg = 0; reg < 4; ++reg) {
            float v = fmaxf(acc[c16][reg] + bias[col], 0.f);
            outb[(rtO * 16 + ktO) * 512 + (g * 4 + reg) * 32 + (col & 31)] = f2b(v);
        }
    }
}

// ---------------- mlp2: out2 = hid @ W2 + b2 + osb, frag A/B/residual + BN3 stats ----------------
__global__ __launch_bounds__(256, 4) void mlp2_k(
    const unsigned short* __restrict__ A,      // hid fragment, KT=16
    const unsigned short* __restrict__ WT,     // W2 fragment, KT=16, 256 cols
    const float* __restrict__ bias,
    const unsigned short* __restrict__ addb,   // osb fragment, KT=8
    float* __restrict__ outf,                  // row-major fp32
    float* __restrict__ gsum, float* __restrict__ gsq)
{
    const int N = Cc;
    const int t = threadIdx.x;
    const int wave = t >> 6, lane = t & 63;
    const int tl = lane & 15, g = lane >> 4;
    const int wr = wave >> 1, wc = wave & 1;
    const int m0 = blockIdx.y * 32, n0 = blockIdx.x * 64;

    __shared__ float csum[64], csq[64];
    if (t < 64) { csum[t] = 0.f; csq[t] = 0.f; }
    __syncthreads();

    f32x4 acc[2] = {};

    const unsigned short* a0 = A  + (size_t)((m0 >> 4) + wr) * 16 * 512 + tl * 32 + g * 8;
    const unsigned short* b0 = WT + ((size_t)(n0 >> 4) + wc * 2) * 16 * 512 + tl * 32 + g * 8;
    const unsigned short* b1 = b0 + 16 * 512;

    for (int k0 = 0; k0 < 512; k0 += 32) {
        bf16x8 af  = ldb8(a0 + (k0 >> 5) * 512);
        bf16x8 bf0 = ldb8(b0 + (k0 >> 5) * 512), bf1 = ldb8(b1 + (k0 >> 5) * 512);
        acc[0] = __builtin_amdgcn_mfma_f32_16x16x32_bf16(af, bf0, acc[0], 0, 0, 0);
        acc[1] = __builtin_amdgcn_mfma_f32_16x16x32_bf16(af, bf1, acc[1], 0, 0, 0);
    }

    const size_t rtR = (size_t)(m0 >> 4) + wr;
    #pragma unroll
    for (int c16 = 0; c16 < 2; ++c16) {
        int colL = wc * 32 + c16 * 16 + tl;
        int col  = n0 + colL;
        int ktR  = col >> 5;
        float ls = 0.f, lq = 0.f;
        #pragma unroll
        for (int reg = 0; reg < 4; ++reg) {
            int row = m0 + wr * 16 + g * 4 + reg;
            float v = acc[c16][reg] + bias[col]
                    + b2f(addb[(rtR * 8 + ktR) * 512 + (g * 4 + reg) * 32 + (col & 31)]);
            ls += v; lq += v * v;
            outf[(size_t)row * N + col] = v;
        }
        atomicAdd(&csum[colL], ls); atomicAdd(&csq[colL], lq);
    }
    __syncthreads();
    if (t < 64) {
        atomicAdd(&gsum[n0 + t], csum[t]);
        atomicAdd(&gsq[n0 + t],  csq[t]);
    }
}

// ---------------- Wo GEMM (A = op0 fragment) + fp32 residual + BN2 stats ----------------
__global__ __launch_bounds__(256, 4) void gemm_attnA_k(
    const unsigned short* __restrict__ op0,    // fragment, KT=8
    const unsigned short* __restrict__ WT, const float* __restrict__ bias,
    const float* __restrict__ add1, unsigned short* __restrict__ h2preb,
    float* __restrict__ gsum, float* __restrict__ gsq)
{
    const int N = Cc;
    const int t = threadIdx.x;
    const int wave = t >> 6, lane = t & 63;
    const int tl = lane & 15, g = lane >> 4;
    const int wr = wave >> 1, wc = wave & 1;
    const int m0 = blockIdx.y * 32, n0 = blockIdx.x * 64;

    __shared__ float csum[64], csq[64];
    if (t < 64) { csum[t] = 0.f; csq[t] = 0.f; }
    __syncthreads();

    f32x4 acc[2] = {};

    const unsigned short* a0b = op0 + (size_t)((m0 >> 4) + wr) * 8 * 512 + tl * 32 + g * 8;
    const unsigned short* b0 = WT + ((size_t)(n0 >> 4) + wc * 2) * 8 * 512 + tl * 32 + g * 8;
    const unsigned short* b1 = b0 + 8 * 512;

    for (int k0 = 0; k0 < 256; k0 += 32) {
        bf16x8 af  = ldb8(a0b + (k0 >> 5) * 512);
        bf16x8 bf0 = ldb8(b0 + (k0 >> 5) * 512), bf1 = ldb8(b1 + (k0 >> 5) * 512);
        acc[0] = __builtin_amdgcn_mfma_f32_16x16x32_bf16(af, bf0, acc[0], 0, 0, 0);
        acc[1] = __builtin_amdgcn_mfma_f32_16x16x32_bf16(af, bf1, acc[1], 0, 0, 0);
    }

    #pragma unroll
    for (int c16 = 0; c16 < 2; ++c16) {
        int colL = wc * 32 + c16 * 16 + tl;
        int col  = n0 + colL;
        float ls = 0.f, lq = 0.f;
        #pragma unroll
        for (int reg = 0; reg < 4; ++reg) {
            int row = m0 + wr * 16 + g * 4 + reg;
            float v = acc[c16][reg] + bias[col];
            size_t idx = (size_t)row * N + col;
            v += add1[idx];
            ls += v; lq += v * v;               // stats in fp32 (pre-rounding)
            h2preb[idx] = f2b(v);
        }
        atomicAdd(&csum[colL], ls); atomicAdd(&csq[colL], lq);
    }
    __syncthreads();
    if (t < 64) {
        atomicAdd(&gsum[n0 + t], csum[t]);
        atomicAdd(&gsq[n0 + t],  csq[t]);
    }
}

// ---------------- BN apply (single, float4) ----------------
__global__ __launch_bounds__(256) void bn_apply_k(
    const float* __restrict__ h, const float* __restrict__ gsum,
    const float* __restrict__ gsq, const float* __restrict__ gamma,
    const float* __restrict__ beta, float* __restrict__ outf)
{
    size_t i4 = ((size_t)blockIdx.x * 256 + threadIdx.x) * 4;
    int ch = (int)(i4 & (Cc - 1));
    float4 hv = *(const float4*)(h + i4);
    float4 sm = *(const float4*)(gsum + ch);
    float4 sq = *(const float4*)(gsq + ch);
    float4 ga = *(const float4*)(gamma + ch);
    float4 be = *(const float4*)(beta + ch);
    float4 o;
    {
        float m = sm.x * (1.f / BNn), var = sq.x * (1.f / BNn) - m * m;
        o.x = (hv.x - m) * rsqrtf(var + EPSV) * ga.x + be.x;
    }
    {
        float m = sm.y * (1.f / BNn), var = sq.y * (1.f / BNn) - m * m;
        o.y = (hv.y - m) * rsqrtf(var + EPSV) * ga.y + be.y;
    }
    {
        float m = sm.z * (1.f / BNn), var = sq.z * (1.f / BNn) - m * m;
        o.z = (hv.z - m) * rsqrtf(var + EPSV) * ga.z + be.z;
    }
    {
        float m = sm.w * (1.f / BNn), var = sq.w * (1.f / BNn) - m * m;
        o.w = (hv.w - m) * rsqrtf(var + EPSV) * ga.w + be.w;
    }
    *(float4*)(outf + i4) = o;
}

// ---------------- fused BN1+BN2 apply -> osb in FRAGMENT layout ----------------
__global__ __launch_bounds__(256) void bn_apply12_k(
    const unsigned short* __restrict__ h1preb, const unsigned short* __restrict__ h2preb,
    const float* __restrict__ stats,
    const float* __restrict__ g1, const float* __restrict__ be1,
    const float* __restrict__ g2, const float* __restrict__ be2,
    unsigned short* __restrict__ outb)         // osb fragment, KT=8
{
    size_t i4 = ((size_t)blockIdx.x * 256 + threadIdx.x) * 4;
    int ch = (int)(i4 & (Cc - 1));
    ushort4 u1 = *(const ushort4*)(h1preb + i4);
    ushort4 u2 = *(const ushort4*)(h2preb + i4);
    float4 s1m = *(const float4*)(stats + ch);
    float4 s1q = *(const float4*)(stats + 256 + ch);
    float4 s2m = *(const float4*)(stats + 512 + ch);
    float4 s2q = *(const float4*)(stats + 768 + ch);
    float4 G1 = *(const float4*)(g1 + ch),  B1 = *(const float4*)(be1 + ch);
    float4 G2 = *(const float4*)(g2 + ch),  B2 = *(const float4*)(be2 + ch);
    ushort4 pk;
    #define BN12C(comp, ucomp) { \
        float m1 = s1m.comp * (1.f / BNn), v1 = s1q.comp * (1.f / BNn) - m1 * m1; \
        float m2 = s2m.comp * (1.f / BNn), v2 = s2q.comp * (1.f / BNn) - m2 * m2; \
        float o = (b2f(u1.ucomp) - m1) * rsqrtf(v1 + EPSV) * G1.comp + B1.comp \
                + (b2f(u2.ucomp) - m2) * rsqrtf(v2 + EPSV) * G2.comp + B2.comp; \
        pk.ucomp = f2b(o); }
    BN12C(x, x) BN12C(y, y) BN12C(z, z) BN12C(w, w)
    #undef BN12C
    int row = (int)(i4 >> 8), col = ch;        // col 4-aligned, stays in one 32-tile
    *(ushort4*)(outb + ((size_t)(row >> 4) * 8 + (col >> 5)) * 512
                + (row & 15) * 32 + (col & 31)) = pk;
}

// ---------------- launch ----------------
extern "C" void kernel_launch(void* const* d_in, const int* in_sizes, int n_in,
                              void* d_out, int out_size, void* d_ws, size_t ws_size,
                              hipStream_t stream)
{
    const float* x   = (const float*)d_in[0];
    const int*   ei  = (const int*)  d_in[1];
    const float* sph = (const float*)d_in[2];
    const float* Wr  = (const float*)d_in[3];
    const float* Wn  = (const float*)d_in[4];
    const float* Wq  = (const float*)d_in[5];
    const float* bq  = (const float*)d_in[6];
    const float* Wk  = (const float*)d_in[7];
    const float* bk  = (const float*)d_in[8];
    const float* Wv  = (const float*)d_in[9];
    const float* bv  = (const float*)d_in[10];
    const float* Wo  = (const float*)d_in[11];
    const float* bo  = (const float*)d_in[12];
    const float* W1  = (const float*)d_in[13];
    const float* b1  = (const float*)d_in[14];
    const float* W2  = (const float*)d_in[15];
    const float* b2  = (const float*)d_in[16];
    const float* g1  = (const float*)d_in[17];
    const float* be1 = (const float*)d_in[18];
    const float* g2  = (const float*)d_in[19];
    const float* be2 = (const float*)d_in[20];
    const float* g3  = (const float*)d_in[21];
    const float* be3 = (const float*)d_in[22];
    float* out = (float*)d_out;

    const size_t SL = (size_t)BNn * Cc;  // 2M elements

    float* ws = (float*)d_ws;
    float* s1 = ws;                  // op0b (bf16 fragment, 4MB)
    float* s2 = s1 + SL;             // h1preb (bf16) then out2 (fp32)
    float* s3 = s2 + SL;             // h2preb (bf16)

    int*   deg      = (int*)(s3 + SL);          // 8192
    float* statsAll = (float*)(deg + 8192);     // 1536
    int*   rowst    = (int*)(statsAll + 1536);  // 8192 (+pad)
    int*   cursor   = rowst + 8256;             // 8192
    int*   eidx     = cursor + 8192;            // 131072

    unsigned short* xf  = (unsigned short*)(eidx + 131072); // fragment; reused as hid
    unsigned short* qb  = xf + 2 * SL;
    unsigned short* kb  = qb + SL;                           // reused as osb (fragment)
    unsigned short* vTb = kb + SL;
    unsigned short* osb = kb;
    unsigned short* hid = xf;

    unsigned short* WcatT = vTb + SL;         // fragment
    unsigned short* WqT   = WcatT + 131072;   // fragment [768 cols][256 K]
    unsigned short* WkT   = WqT + 65536;
    unsigned short* WvT   = WkT + 65536;
    unsigned short* WoT   = WvT + 65536;
    unsigned short* W1T   = WoT + 65536;
    unsigned short* W2T   = W1T + 131072;
    unsigned short* xlo   = W2T + 131072;     // row-major bf16 x copy [8192][256]
    unsigned short* op0b   = (unsigned short*)s1;
    unsigned short* h1preb = (unsigned short*)s2;   // 4MB of s2; dead before out2
    unsigned short* h2preb = (unsigned short*)s3;

    dim3 gN256(4, 256);
    dim3 gN512(8, 256);

    const float QSCALE = 0.17677669529663687f * 1.4426950408889634f;

    // 1) zero deg + all BN stats in one memset
    hipMemsetAsync(deg, 0, (8192 + 1536) * sizeof(float), stream);
    // 2) fused converts + histogram (fragment weight layouts + xlo copy)
    prep_k<<<5120, 256, 0, stream>>>(x, xf, xlo, Wr, Wn, Wq, Wk, Wv, Wo, W1, W2,
                                     WcatT, WqT, WkT, WvT, WoT, W1T, W2T, ei, deg);
    // 3-4) CSR scan / place
    scan_k<<<1, 256, 0, stream>>>(deg, rowst, cursor);
    place_k<<<Ee / 256, 256, 0, stream>>>(ei, cursor, eidx);
    // 5) gather (xlo -> xf hi kts) || QKV GEMM (frag A/B + frag K/V out)
    gather_qkv_k<<<5120, 256, 0, stream>>>(xlo, rowst, deg, eidx, xf,
                                           WqT, bq, bk, bv, qb, kb, vTb, QSCALE);
    // 6) attention (frag K/V, frag O out) || h1pre GEMM (frag A/B) — 768 blocks
    attn_h1_k<<<768, 512, 0, stream>>>(qb, kb, vTb, sph, op0b,
                                       xf, WcatT, x, h1preb,
                                       statsAll, statsAll + 256);
    // 7) h2pre = O @ Wo + bo + x -> bf16, + BN2 stats (frag A)
    gemm_attnA_k<<<gN256, 256, 0, stream>>>(op0b, WoT, bo, x,
                                            h2preb, statsAll + 512, statsAll + 768);
    // 8) osb(frag) = bn1(h1pre) + bn2(h2pre)
    bn_apply12_k<<<(int)(SL / 1024), 256, 0, stream>>>(h1preb, h2preb, statsAll,
                                                       g1, be1, g2, be2, osb);
    // 9) hid(frag) = relu(osb @ W1 + b1)
    mlp1_k<<<gN512, 256, 0, stream>>>(osb, W1T, b1, hid);
    // 10) out2 = hid @ W2 + b2 + osb(frag residual) -> s2 fp32, + BN3 stats
    mlp2_k<<<gN256, 256, 0, stream>>>(hid, W2T, b2, osb, s2,
                                      statsAll + 1024, statsAll + 1280);
    // 11) d_out = BN3(out2)
    bn_apply_k<<<(int)(SL / 1024), 256, 0, stream>>>(s2, statsAll + 1024,
                                                     statsAll + 1280, g3, be3, out);
}